// Round 9
// baseline (9123.534 us; speedup 1.0000x reference)
//
#include <hip/hip_runtime.h>
#include <hip/hip_bf16.h>

#define N_PTS 16384
#define M_CTR 4096
#define NIN   64
#define NOUT  128
#define DIM   67
#define KNBR  64
#define R2    0.25f
#define BNI   0.9999950000374997f   // 1/sqrt(1+1e-5)

// ws layout (bytes): sel int[4096] @0 ; nvalid int[4096] @16384 ; nbr int[4096*64] @32768 ;
//                    U float[16384*67] @1081344 (ends 5472256) — used only if ws_size permits

typedef float v2f __attribute__((ext_vector_type(2)));

// packed f32 ops: identical IEEE-rn semantics to scalar v_add/v_mul, 2 lanes at once
static __device__ inline v2f pk_add(v2f a, v2f b) {
  v2f d; asm("v_pk_add_f32 %0, %1, %2" : "=v"(d) : "v"(a), "v"(b)); return d;
}
static __device__ inline v2f pk_mul(v2f a, v2f b) {
  v2f d; asm("v_pk_mul_f32 %0, %1, %2" : "=v"(d) : "v"(a), "v"(b)); return d;
}

__device__ inline unsigned long long shfl_xor_u64(unsigned long long v, int m){
  int lo = __shfl_xor((int)(unsigned)v, m, 64);
  int hi = __shfl_xor((int)(unsigned)(v >> 32), m, 64);
  return ((unsigned long long)(unsigned)hi << 32) | (unsigned)lo;
}
__device__ inline unsigned long long u64max(unsigned long long a, unsigned long long b){
  return a > b ? a : b;
}

// ---------------- FPS: single block, 1024 thr, packed math ------------------
#define FPS_T 1024
#define FPS_K (N_PTS / FPS_T)   // 16 points per thread, strided ownership
#define FPS_K2 (FPS_K / 2)
#define FPS_W (FPS_T / 64)      // 16 waves

__global__ __launch_bounds__(FPS_T, 4) void fps_kernel(const float* __restrict__ pos,
                                                       int* __restrict__ sel) {
  __shared__ __align__(16) unsigned long long wkey[2][FPS_W];  // parity double-buffer
  const int t = threadIdx.x;
  v2f px[FPS_K2], py[FPS_K2], pz[FPS_K2];
  float dmin[FPS_K];
#pragma unroll
  for (int j = 0; j < FPS_K2; j++) {
    int g0 = t + FPS_T * (2*j);
    int g1 = t + FPS_T * (2*j + 1);
    px[j] = (v2f){pos[3*g0+0], pos[3*g1+0]};
    py[j] = (v2f){pos[3*g0+1], pos[3*g1+1]};
    pz[j] = (v2f){pos[3*g0+2], pos[3*g1+2]};
    dmin[2*j] = 3.4028235e38f; dmin[2*j+1] = 3.4028235e38f;
  }
  if (t == 0) sel[0] = 0;
  float X = pos[0], Y = pos[1], Z = pos[2];
  for (int s = 1; s < M_CTR; s++) {
    // ---- distance + dmin update (packed, exact: q = (dx*dx+dy*dy)+dz*dz rn) ----
    const float nX = -X, nY = -Y, nZ = -Z;
    const v2f nXX = (v2f){nX, nX}, nYY = (v2f){nY, nY}, nZZ = (v2f){nZ, nZ};
#pragma unroll
    for (int j = 0; j < FPS_K2; j++) {
      v2f dx = pk_add(px[j], nXX);       // p - X  (add of exact negation == fsub_rn)
      v2f dy = pk_add(py[j], nYY);
      v2f dz = pk_add(pz[j], nZZ);
      v2f xx = pk_mul(dx, dx);
      v2f yy = pk_mul(dy, dy);
      v2f zz = pk_mul(dz, dz);
      v2f ss = pk_add(xx, yy);
      v2f qq = pk_add(ss, zz);
      dmin[2*j]   = fminf(dmin[2*j],   qq.x);
      dmin[2*j+1] = fminf(dmin[2*j+1], qq.y);
    }
    // ---- deferred argmax: max tree (v), then first-k equality scan (iL) ----
    float m0 = fmaxf(fmaxf(dmin[0], dmin[1]), fmaxf(dmin[2], dmin[3]));
    float m1 = fmaxf(fmaxf(dmin[4], dmin[5]), fmaxf(dmin[6], dmin[7]));
    float m2 = fmaxf(fmaxf(dmin[8], dmin[9]), fmaxf(dmin[10], dmin[11]));
    float m3 = fmaxf(fmaxf(dmin[12], dmin[13]), fmaxf(dmin[14], dmin[15]));
    float v = fmaxf(fmaxf(m0, m1), fmaxf(m2, m3));
    int iL = 0;
#pragma unroll
    for (int k = FPS_K - 1; k >= 0; k--) iL = (dmin[k] == v) ? k : iL;  // earliest k wins
    unsigned g = (unsigned)t + ((unsigned)iL * FPS_T);
    unsigned long long key =
        (((unsigned long long)__float_as_uint(v)) << 32) |
        (unsigned long long)(0xFFFFFFFFu - g);   // larger val wins; ties -> smaller idx
#pragma unroll
    for (int m = 32; m >= 1; m >>= 1) {
      unsigned long long o = shfl_xor_u64(key, m);
      key = (o > key) ? o : key;
    }
    if ((t & 63) == 0) wkey[s & 1][t >> 6] = key;
    __syncthreads();                              // the ONLY barrier this round
    // every thread redundantly reduces the 16 wave keys (b128 reads + tree)
    const ulonglong2* wk2 = (const ulonglong2*)&wkey[s & 1][0];
    ulonglong2 p0 = wk2[0], p1 = wk2[1], p2 = wk2[2], p3 = wk2[3];
    ulonglong2 p4 = wk2[4], p5 = wk2[5], p6 = wk2[6], p7 = wk2[7];
    unsigned long long a0 = u64max(u64max(p0.x, p0.y), u64max(p1.x, p1.y));
    unsigned long long a1 = u64max(u64max(p2.x, p2.y), u64max(p3.x, p3.y));
    unsigned long long a2 = u64max(u64max(p4.x, p4.y), u64max(p5.x, p5.y));
    unsigned long long a3 = u64max(u64max(p6.x, p6.y), u64max(p7.x, p7.y));
    unsigned long long kb = u64max(u64max(a0, a1), u64max(a2, a3));
    unsigned gw = 0xFFFFFFFFu - (unsigned)(kb & 0xFFFFFFFFull);
    if (t == 0) sel[s] = (int)gw;
    // same-address global load: one L1-hit fetch, broadcast to all lanes
    X = pos[3*gw+0]; Y = pos[3*gw+1]; Z = pos[3*gw+2];
  }
}

// ---------------- precompute U = x @ w1[:64,:] ------------------------------
__global__ __launch_bounds__(64) void xw1_kernel(const float* __restrict__ x,
                                                 const float* __restrict__ w1,
                                                 float* __restrict__ U) {
  __shared__ float xs[NIN];
  const int n = blockIdx.x, t = threadIdx.x;
  xs[t] = x[n * NIN + t];
  __syncthreads();
  for (int c = t; c < DIM; c += 64) {
    float acc = 0.0f;
#pragma unroll 8
    for (int r = 0; r < NIN; r++) acc = fmaf(xs[r], w1[r * DIM + c], acc);
    U[n * DIM + c] = acc;
  }
}

// ---------------- ball query: one WAVE per centroid -------------------------
#define CAP 2048
__global__ __launch_bounds__(64) void ballq_kernel(const float* __restrict__ pos,
                                                   const int* __restrict__ sel,
                                                   int* __restrict__ nbr,
                                                   int* __restrict__ nvalid) {
  __shared__ unsigned long long keys[CAP];
  __shared__ int cnt;
  const int i = blockIdx.x;
  const int lane = threadIdx.x;
  if (lane == 0) cnt = 0;
  __syncthreads();
  int ci = sel[i]; ci = min(max(ci, 0), N_PTS - 1);
  const float X = pos[3*ci], Y = pos[3*ci+1], Z = pos[3*ci+2];
  for (int k = 0; k < N_PTS / 64; k++) {
    int g = lane + 64 * k;
    float dx = __fsub_rn(pos[3*g+0], X);
    float dy = __fsub_rn(pos[3*g+1], Y);
    float dz = __fsub_rn(pos[3*g+2], Z);
    float q  = __fadd_rn(__fadd_rn(__fmul_rn(dx,dx), __fmul_rn(dy,dy)), __fmul_rn(dz,dz));
    if (q <= R2) {
      int p = atomicAdd(&cnt, 1);
      if (p < CAP)
        keys[p] = (((unsigned long long)__float_as_uint(q)) << 32) | (unsigned)g;
    }
  }
  __syncthreads();
  const int n = min(cnt, CAP);
  for (int r = 0; r < KNBR; r++) {
    unsigned long long mk = ~0ull; int mp = -1;
    for (int p = lane; p < n; p += 64) {
      unsigned long long kk = keys[p];
      if (kk < mk) { mk = kk; mp = p; }
    }
    unsigned long long rk = mk;
#pragma unroll
    for (int m = 32; m >= 1; m >>= 1) {
      unsigned long long o = shfl_xor_u64(rk, m);
      rk = (o < rk) ? o : rk;
    }
    if (rk != ~0ull && rk == mk && mp >= 0) keys[mp] = ~0ull;  // unique winner clears own slot
    if (lane == 0)
      nbr[i * KNBR + r] = (rk != ~0ull) ? (int)(unsigned)(rk & 0xFFFFFFFFull) : 0;
  }
  if (lane == 0) nvalid[i] = min(n, KNBR);
}

// ---------------- MLP (U-precomputed path): w2 column in registers ----------
__global__ __launch_bounds__(128) void mlp_u_kernel(
    const float* __restrict__ U, const float* __restrict__ pos,
    const float* __restrict__ w1, const float* __restrict__ b1,
    const float* __restrict__ g1, const float* __restrict__ be1,
    const float* __restrict__ w2, const float* __restrict__ b2,
    const float* __restrict__ g2, const float* __restrict__ be2,
    const int* __restrict__ sel, const int* __restrict__ nbr,
    const int* __restrict__ nvalid, float* __restrict__ out) {
  __shared__ float Us[KNBR * DIM];
  __shared__ float relx[KNBR], rely[KNBR], relz[KNBR];
  __shared__ float h1[DIM];
  __shared__ float w1r[3][DIM], b1s[DIM], g1s[DIM], be1s[DIM];
  __shared__ int nbrs_s[KNBR];
  const int i = blockIdx.x, t = threadIdx.x;
  int nv = nvalid[i]; nv = min(max(nv, 0), KNBR);
  float w2r[DIM];
#pragma unroll
  for (int c = 0; c < DIM; c++) w2r[c] = w2[c * NOUT + t];
  if (t < KNBR) {
    int nj = (t < nv) ? nbr[i * KNBR + t] : 0;
    nbrs_s[t] = min(max(nj, 0), N_PTS - 1);
  }
  if (t < DIM) {
    w1r[0][t] = w1[64*DIM + t]; w1r[1][t] = w1[65*DIM + t]; w1r[2][t] = w1[66*DIM + t];
    b1s[t] = b1[t]; g1s[t] = g1[t]; be1s[t] = be1[t];
  }
  __syncthreads();
  int ci = sel[i]; ci = min(max(ci, 0), N_PTS - 1);
  const float cx = pos[3*ci], cy = pos[3*ci+1], cz = pos[3*ci+2];
  if (t < KNBR && t < nv) {
    int nj = nbrs_s[t];
    relx[t] = pos[3*nj+0] - cx; rely[t] = pos[3*nj+1] - cy; relz[t] = pos[3*nj+2] - cz;
  }
  for (int e = t; e < nv * DIM; e += 128) {
    int r = e / DIM, c = e - r * DIM;
    Us[e] = U[nbrs_s[r] * DIM + c];
  }
  __syncthreads();
  const float b2d = b2[t], g2d = g2[t], be2d = be2[t];
  float omax = -3.4028235e38f;
  for (int j = 0; j < nv; j++) {
    if (t < DIM) {
      float z = Us[j*DIM + t];
      z = fmaf(relx[j], w1r[0][t], z);
      z = fmaf(rely[j], w1r[1][t], z);
      z = fmaf(relz[j], w1r[2][t], z);
      z += b1s[t];
      z = fmaxf(z, 0.0f);
      h1[t] = g1s[t] * (z * BNI) + be1s[t];
    }
    __syncthreads();
    float a0 = 0.f, a1 = 0.f, a2 = 0.f, a3 = 0.f;
#pragma unroll
    for (int c = 0; c < 64; c += 4) {
      a0 = fmaf(h1[c+0], w2r[c+0], a0);
      a1 = fmaf(h1[c+1], w2r[c+1], a1);
      a2 = fmaf(h1[c+2], w2r[c+2], a2);
      a3 = fmaf(h1[c+3], w2r[c+3], a3);
    }
    a0 = fmaf(h1[64], w2r[64], a0);
    a1 = fmaf(h1[65], w2r[65], a1);
    a2 = fmaf(h1[66], w2r[66], a2);
    float acc = ((a0 + a1) + (a2 + a3)) + b2d;
    float h2v = g2d * (fmaxf(acc, 0.0f) * BNI) + be2d;
    omax = fmaxf(omax, h2v);
    __syncthreads();
  }
  if (nv == 0) omax = 0.0f;
  out[i*NOUT + t] = omax;
}

// ---------------- MLP fallback (reads x directly) ---------------------------
__global__ __launch_bounds__(128) void mlp_direct_kernel(
    const float* __restrict__ x, const float* __restrict__ pos,
    const float* __restrict__ w1, const float* __restrict__ b1,
    const float* __restrict__ g1, const float* __restrict__ be1,
    const float* __restrict__ w2, const float* __restrict__ b2,
    const float* __restrict__ g2, const float* __restrict__ be2,
    const int* __restrict__ sel, const int* __restrict__ nbr,
    const int* __restrict__ nvalid, float* __restrict__ out) {
  __shared__ float xs[NIN];
  __shared__ float h1[DIM];
  __shared__ float rel[3];
  const int i = blockIdx.x, t = threadIdx.x;
  int ci = sel[i]; ci = min(max(ci, 0), N_PTS - 1);
  const float cx = pos[3*ci], cy = pos[3*ci+1], cz = pos[3*ci+2];
  int nv = nvalid[i]; nv = min(max(nv, 0), KNBR);
  float omax = -3.4028235e38f;
  for (int j = 0; j < nv; j++) {
    int nj = nbr[i*KNBR + j]; nj = min(max(nj, 0), N_PTS - 1);
    if (t < NIN) xs[t] = x[nj*NIN + t];
    if (t == 0) { rel[0] = pos[3*nj]-cx; rel[1] = pos[3*nj+1]-cy; rel[2] = pos[3*nj+2]-cz; }
    __syncthreads();
    if (t < DIM) {
      float z = b1[t];
      for (int r = 0; r < NIN; r++) z = fmaf(xs[r], w1[r*DIM + t], z);
      z = fmaf(rel[0], w1[64*DIM + t], z);
      z = fmaf(rel[1], w1[65*DIM + t], z);
      z = fmaf(rel[2], w1[66*DIM + t], z);
      z = fmaxf(z, 0.0f);
      h1[t] = g1[t] * (z * BNI) + be1[t];
    }
    __syncthreads();
    float acc = b2[t];
    for (int c = 0; c < DIM; c++) acc = fmaf(h1[c], w2[c*NOUT + t], acc);
    float h2v = g2[t] * (fmaxf(acc, 0.0f) * BNI) + be2[t];
    omax = fmaxf(omax, h2v);
    __syncthreads();
  }
  if (nv == 0) omax = 0.0f;
  out[i*NOUT + t] = omax;
}

// ---------------- finalize: pos_s, batch, idx (float32 out) -----------------
__global__ void fin_kernel(const float* __restrict__ pos, const int* __restrict__ batch,
                           const int* __restrict__ sel, float* __restrict__ out) {
  int i = blockIdx.x * blockDim.x + threadIdx.x;
  if (i < M_CTR) {
    int s = sel[i];
    int sc = min(max(s, 0), N_PTS - 1);
    out[M_CTR*NOUT + 3*i + 0] = pos[3*sc+0];
    out[M_CTR*NOUT + 3*i + 1] = pos[3*sc+1];
    out[M_CTR*NOUT + 3*i + 2] = pos[3*sc+2];
    out[M_CTR*NOUT + 3*M_CTR + i] = (float)batch[sc];
    out[M_CTR*NOUT + 4*M_CTR + i] = (float)s;
  }
}

extern "C" void kernel_launch(void* const* d_in, const int* in_sizes, int n_in,
                              void* d_out, int out_size, void* d_ws, size_t ws_size,
                              hipStream_t stream) {
  const float* x   = (const float*)d_in[0];
  const float* pos = (const float*)d_in[1];
  const int*  batch= (const int*)d_in[2];
  const float* w1  = (const float*)d_in[3];
  const float* b1  = (const float*)d_in[4];
  const float* g1  = (const float*)d_in[5];
  const float* be1 = (const float*)d_in[6];
  const float* w2  = (const float*)d_in[7];
  const float* b2  = (const float*)d_in[8];
  const float* g2  = (const float*)d_in[9];
  const float* be2 = (const float*)d_in[10];
  float* out = (float*)d_out;

  char*  ws   = (char*)d_ws;
  int*   sel  = (int*)(ws);
  int*   nvld = (int*)(ws + 16384);
  int*   nbr  = (int*)(ws + 32768);
  float* U    = (float*)(ws + 1081344);
  const bool useU = (ws_size >= (size_t)1081344 + (size_t)N_PTS * DIM * 4);

  hipLaunchKernelGGL(fps_kernel,   dim3(1),      dim3(FPS_T), 0, stream, pos, sel);
  hipLaunchKernelGGL(ballq_kernel, dim3(M_CTR),  dim3(64),    0, stream, pos, sel, nbr, nvld);
  if (useU) {
    hipLaunchKernelGGL(xw1_kernel, dim3(N_PTS),  dim3(64),    0, stream, x, w1, U);
    hipLaunchKernelGGL(mlp_u_kernel, dim3(M_CTR), dim3(128),  0, stream,
                       U, pos, w1, b1, g1, be1, w2, b2, g2, be2, sel, nbr, nvld, out);
  } else {
    hipLaunchKernelGGL(mlp_direct_kernel, dim3(M_CTR), dim3(128), 0, stream,
                       x, pos, w1, b1, g1, be1, w2, b2, g2, be2, sel, nbr, nvld, out);
  }
  hipLaunchKernelGGL(fin_kernel,   dim3(16),     dim3(256),   0, stream, pos, batch, sel, out);
}

// Round 11
// 8098.200 us; speedup vs baseline: 1.1266x; 1.1266x over previous
//
#include <hip/hip_runtime.h>
#include <hip/hip_bf16.h>

#define N_PTS 16384
#define M_CTR 4096
#define NIN   64
#define NOUT  128
#define DIM   67
#define KNBR  64
#define R2    0.25f
#define BNI   0.9999950000374997f   // 1/sqrt(1+1e-5)

// ws layout (bytes): sel int[4096] @0 ; nvalid int[4096] @16384 ; nbr int[4096*64] @32768 ;
//                    U float[16384*67] @1081344 (ends 5472256) — used only if ws_size permits

__device__ inline unsigned long long shfl_xor_u64(unsigned long long v, int m){
  int lo = __shfl_xor((int)(unsigned)v, m, 64);
  int hi = __shfl_xor((int)(unsigned)(v >> 32), m, 64);
  return ((unsigned long long)(unsigned)hi << 32) | (unsigned)lo;
}
__device__ inline unsigned long long u64max(unsigned long long a, unsigned long long b){
  return a > b ? a : b;
}
// ds_swizzle xor-butterfly within 32-lane halves (BitMode: (xor<<10)|0x1F)
// pattern must be an integer-constant-expression -> template parameter
template<int PAT>
__device__ inline float swz_xor_f(float x){
  return __int_as_float(__builtin_amdgcn_ds_swizzle(__float_as_int(x), PAT));
}
template<int PAT>
__device__ inline unsigned swz_xor_u(unsigned x){
  return (unsigned)__builtin_amdgcn_ds_swizzle((int)x, PAT);
}

// ---------------- FPS: single block, 1024 thr, exact numpy rounding ---------
#define FPS_T 1024
#define FPS_K (N_PTS / FPS_T)   // 16 points per thread, strided ownership
#define FPS_W (FPS_T / 64)      // 16 waves

__global__ __launch_bounds__(FPS_T, 4) void fps_kernel(const float* __restrict__ pos,
                                                       int* __restrict__ sel) {
  __shared__ __align__(16) unsigned long long wkey[2][FPS_W];  // parity double-buffer
  const int t = threadIdx.x;
  float px[FPS_K], py[FPS_K], pz[FPS_K], dmin[FPS_K];
#pragma unroll
  for (int k = 0; k < FPS_K; k++) {
    int g = t + FPS_T * k;
    px[k] = pos[3*g+0]; py[k] = pos[3*g+1]; pz[k] = pos[3*g+2];
    dmin[k] = 3.4028235e38f;
  }
  if (t == 0) sel[0] = 0;
  float X = pos[0], Y = pos[1], Z = pos[2];
  for (int s = 1; s < M_CTR; s++) {
    // ---- dmin update: exact (p-c)^2, no fma contraction, (xx+yy)+zz order ----
#pragma unroll
    for (int k = 0; k < FPS_K; k++) {
      float dx = __fsub_rn(px[k], X);
      float dy = __fsub_rn(py[k], Y);
      float dz = __fsub_rn(pz[k], Z);
      float q  = __fadd_rn(__fadd_rn(__fmul_rn(dx,dx), __fmul_rn(dy,dy)), __fmul_rn(dz,dz));
      dmin[k]  = fminf(dmin[k], q);
    }
    // ---- deferred argmax: balanced max tree (v_max3-friendly), then earliest-k scan ----
    float m0 = fmaxf(fmaxf(dmin[0],  dmin[1]),  fmaxf(dmin[2],  dmin[3]));
    float m1 = fmaxf(fmaxf(dmin[4],  dmin[5]),  fmaxf(dmin[6],  dmin[7]));
    float m2 = fmaxf(fmaxf(dmin[8],  dmin[9]),  fmaxf(dmin[10], dmin[11]));
    float m3 = fmaxf(fmaxf(dmin[12], dmin[13]), fmaxf(dmin[14], dmin[15]));
    float v  = fmaxf(fmaxf(m0, m1), fmaxf(m2, m3));
    int iL = 0;
#pragma unroll
    for (int k = FPS_K - 1; k >= 0; k--) iL = (dmin[k] == v) ? k : iL;  // earliest k wins
    unsigned g = (unsigned)t + ((unsigned)iL << 10);   // global index of my candidate
    // ---- intra-wave reduce, two-phase (exact ≡ u64-key max) ----
    // phase 1: wave max of v (f32 >= 0, so float order == uint order)
    float wv = v;
    wv = fmaxf(wv, swz_xor_f<0x041F>(wv));             // xor 1
    wv = fmaxf(wv, swz_xor_f<0x081F>(wv));             // xor 2
    wv = fmaxf(wv, swz_xor_f<0x101F>(wv));             // xor 4
    wv = fmaxf(wv, swz_xor_f<0x201F>(wv));             // xor 8
    wv = fmaxf(wv, swz_xor_f<0x401F>(wv));             // xor 16
    wv = fmaxf(wv, __int_as_float(__shfl_xor(__float_as_int(wv), 32, 64)));  // xor 32
    // phase 2: min g among lanes holding wv (ties -> smallest global index)
    unsigned c = (v == wv) ? g : 0xFFFFFFFFu;
    c = min(c, swz_xor_u<0x041F>(c));
    c = min(c, swz_xor_u<0x081F>(c));
    c = min(c, swz_xor_u<0x101F>(c));
    c = min(c, swz_xor_u<0x201F>(c));
    c = min(c, swz_xor_u<0x401F>(c));
    c = min(c, (unsigned)__shfl_xor((int)c, 32, 64));
    if ((t & 63) == 0)
      wkey[s & 1][t >> 6] = (((unsigned long long)__float_as_uint(wv)) << 32) |
                            (unsigned long long)(0xFFFFFFFFu - c);
    __syncthreads();                              // the ONLY barrier this round
    // every thread redundantly reduces the 16 wave keys (b128 reads + tree)
    const ulonglong2* wk2 = (const ulonglong2*)&wkey[s & 1][0];
    ulonglong2 p0 = wk2[0], p1 = wk2[1], p2 = wk2[2], p3 = wk2[3];
    ulonglong2 p4 = wk2[4], p5 = wk2[5], p6 = wk2[6], p7 = wk2[7];
    unsigned long long a0 = u64max(u64max(p0.x, p0.y), u64max(p1.x, p1.y));
    unsigned long long a1 = u64max(u64max(p2.x, p2.y), u64max(p3.x, p3.y));
    unsigned long long a2 = u64max(u64max(p4.x, p4.y), u64max(p5.x, p5.y));
    unsigned long long a3 = u64max(u64max(p6.x, p6.y), u64max(p7.x, p7.y));
    unsigned long long kb = u64max(u64max(a0, a1), u64max(a2, a3));
    unsigned gw = 0xFFFFFFFFu - (unsigned)(kb & 0xFFFFFFFFull);
    if (t == 0) sel[s] = (int)gw;
    // same-address global load: one L1-hit fetch, broadcast to all lanes
    X = pos[3*gw+0]; Y = pos[3*gw+1]; Z = pos[3*gw+2];
  }
}

// ---------------- precompute U = x @ w1[:64,:] ------------------------------
__global__ __launch_bounds__(64) void xw1_kernel(const float* __restrict__ x,
                                                 const float* __restrict__ w1,
                                                 float* __restrict__ U) {
  __shared__ float xs[NIN];
  const int n = blockIdx.x, t = threadIdx.x;
  xs[t] = x[n * NIN + t];
  __syncthreads();
  for (int c = t; c < DIM; c += 64) {
    float acc = 0.0f;
#pragma unroll 8
    for (int r = 0; r < NIN; r++) acc = fmaf(xs[r], w1[r * DIM + c], acc);
    U[n * DIM + c] = acc;
  }
}

// ---------------- ball query: one WAVE per centroid -------------------------
#define CAP 2048
__global__ __launch_bounds__(64) void ballq_kernel(const float* __restrict__ pos,
                                                   const int* __restrict__ sel,
                                                   int* __restrict__ nbr,
                                                   int* __restrict__ nvalid) {
  __shared__ unsigned long long keys[CAP];
  __shared__ int cnt;
  const int i = blockIdx.x;
  const int lane = threadIdx.x;
  if (lane == 0) cnt = 0;
  __syncthreads();
  int ci = sel[i]; ci = min(max(ci, 0), N_PTS - 1);
  const float X = pos[3*ci], Y = pos[3*ci+1], Z = pos[3*ci+2];
  for (int k = 0; k < N_PTS / 64; k++) {
    int g = lane + 64 * k;
    float dx = __fsub_rn(pos[3*g+0], X);
    float dy = __fsub_rn(pos[3*g+1], Y);
    float dz = __fsub_rn(pos[3*g+2], Z);
    float q  = __fadd_rn(__fadd_rn(__fmul_rn(dx,dx), __fmul_rn(dy,dy)), __fmul_rn(dz,dz));
    if (q <= R2) {
      int p = atomicAdd(&cnt, 1);
      if (p < CAP)
        keys[p] = (((unsigned long long)__float_as_uint(q)) << 32) | (unsigned)g;
    }
  }
  __syncthreads();
  const int n = min(cnt, CAP);
  for (int r = 0; r < KNBR; r++) {
    unsigned long long mk = ~0ull; int mp = -1;
    for (int p = lane; p < n; p += 64) {
      unsigned long long kk = keys[p];
      if (kk < mk) { mk = kk; mp = p; }
    }
    unsigned long long rk = mk;
#pragma unroll
    for (int m = 32; m >= 1; m >>= 1) {
      unsigned long long o = shfl_xor_u64(rk, m);
      rk = (o < rk) ? o : rk;
    }
    if (rk != ~0ull && rk == mk && mp >= 0) keys[mp] = ~0ull;  // unique winner clears own slot
    if (lane == 0)
      nbr[i * KNBR + r] = (rk != ~0ull) ? (int)(unsigned)(rk & 0xFFFFFFFFull) : 0;
  }
  if (lane == 0) nvalid[i] = min(n, KNBR);
}

// ---------------- MLP (U-precomputed path): w2 column in registers ----------
__global__ __launch_bounds__(128) void mlp_u_kernel(
    const float* __restrict__ U, const float* __restrict__ pos,
    const float* __restrict__ w1, const float* __restrict__ b1,
    const float* __restrict__ g1, const float* __restrict__ be1,
    const float* __restrict__ w2, const float* __restrict__ b2,
    const float* __restrict__ g2, const float* __restrict__ be2,
    const int* __restrict__ sel, const int* __restrict__ nbr,
    const int* __restrict__ nvalid, float* __restrict__ out) {
  __shared__ float Us[KNBR * DIM];
  __shared__ float relx[KNBR], rely[KNBR], relz[KNBR];
  __shared__ float h1[DIM];
  __shared__ float w1r[3][DIM], b1s[DIM], g1s[DIM], be1s[DIM];
  __shared__ int nbrs_s[KNBR];
  const int i = blockIdx.x, t = threadIdx.x;
  int nv = nvalid[i]; nv = min(max(nv, 0), KNBR);
  float w2r[DIM];
#pragma unroll
  for (int c = 0; c < DIM; c++) w2r[c] = w2[c * NOUT + t];
  if (t < KNBR) {
    int nj = (t < nv) ? nbr[i * KNBR + t] : 0;
    nbrs_s[t] = min(max(nj, 0), N_PTS - 1);
  }
  if (t < DIM) {
    w1r[0][t] = w1[64*DIM + t]; w1r[1][t] = w1[65*DIM + t]; w1r[2][t] = w1[66*DIM + t];
    b1s[t] = b1[t]; g1s[t] = g1[t]; be1s[t] = be1[t];
  }
  __syncthreads();
  int ci = sel[i]; ci = min(max(ci, 0), N_PTS - 1);
  const float cx = pos[3*ci], cy = pos[3*ci+1], cz = pos[3*ci+2];
  if (t < KNBR && t < nv) {
    int nj = nbrs_s[t];
    relx[t] = pos[3*nj+0] - cx; rely[t] = pos[3*nj+1] - cy; relz[t] = pos[3*nj+2] - cz;
  }
  for (int e = t; e < nv * DIM; e += 128) {
    int r = e / DIM, c = e - r * DIM;
    Us[e] = U[nbrs_s[r] * DIM + c];
  }
  __syncthreads();
  const float b2d = b2[t], g2d = g2[t], be2d = be2[t];
  float omax = -3.4028235e38f;
  for (int j = 0; j < nv; j++) {
    if (t < DIM) {
      float z = Us[j*DIM + t];
      z = fmaf(relx[j], w1r[0][t], z);
      z = fmaf(rely[j], w1r[1][t], z);
      z = fmaf(relz[j], w1r[2][t], z);
      z += b1s[t];
      z = fmaxf(z, 0.0f);
      h1[t] = g1s[t] * (z * BNI) + be1s[t];
    }
    __syncthreads();
    float a0 = 0.f, a1 = 0.f, a2 = 0.f, a3 = 0.f;
#pragma unroll
    for (int c = 0; c < 64; c += 4) {
      a0 = fmaf(h1[c+0], w2r[c+0], a0);
      a1 = fmaf(h1[c+1], w2r[c+1], a1);
      a2 = fmaf(h1[c+2], w2r[c+2], a2);
      a3 = fmaf(h1[c+3], w2r[c+3], a3);
    }
    a0 = fmaf(h1[64], w2r[64], a0);
    a1 = fmaf(h1[65], w2r[65], a1);
    a2 = fmaf(h1[66], w2r[66], a2);
    float acc = ((a0 + a1) + (a2 + a3)) + b2d;
    float h2v = g2d * (fmaxf(acc, 0.0f) * BNI) + be2d;
    omax = fmaxf(omax, h2v);
    __syncthreads();
  }
  if (nv == 0) omax = 0.0f;
  out[i*NOUT + t] = omax;
}

// ---------------- MLP fallback (reads x directly) ---------------------------
__global__ __launch_bounds__(128) void mlp_direct_kernel(
    const float* __restrict__ x, const float* __restrict__ pos,
    const float* __restrict__ w1, const float* __restrict__ b1,
    const float* __restrict__ g1, const float* __restrict__ be1,
    const float* __restrict__ w2, const float* __restrict__ b2,
    const float* __restrict__ g2, const float* __restrict__ be2,
    const int* __restrict__ sel, const int* __restrict__ nbr,
    const int* __restrict__ nvalid, float* __restrict__ out) {
  __shared__ float xs[NIN];
  __shared__ float h1[DIM];
  __shared__ float rel[3];
  const int i = blockIdx.x, t = threadIdx.x;
  int ci = sel[i]; ci = min(max(ci, 0), N_PTS - 1);
  const float cx = pos[3*ci], cy = pos[3*ci+1], cz = pos[3*ci+2];
  int nv = nvalid[i]; nv = min(max(nv, 0), KNBR);
  float omax = -3.4028235e38f;
  for (int j = 0; j < nv; j++) {
    int nj = nbr[i*KNBR + j]; nj = min(max(nj, 0), N_PTS - 1);
    if (t < NIN) xs[t] = x[nj*NIN + t];
    if (t == 0) { rel[0] = pos[3*nj]-cx; rel[1] = pos[3*nj+1]-cy; rel[2] = pos[3*nj+2]-cz; }
    __syncthreads();
    if (t < DIM) {
      float z = b1[t];
      for (int r = 0; r < NIN; r++) z = fmaf(xs[r], w1[r*DIM + t], z);
      z = fmaf(rel[0], w1[64*DIM + t], z);
      z = fmaf(rel[1], w1[65*DIM + t], z);
      z = fmaf(rel[2], w1[66*DIM + t], z);
      z = fmaxf(z, 0.0f);
      h1[t] = g1[t] * (z * BNI) + be1[t];
    }
    __syncthreads();
    float acc = b2[t];
    for (int c = 0; c < DIM; c++) acc = fmaf(h1[c], w2[c*NOUT + t], acc);
    float h2v = g2[t] * (fmaxf(acc, 0.0f) * BNI) + be2[t];
    omax = fmaxf(omax, h2v);
    __syncthreads();
  }
  if (nv == 0) omax = 0.0f;
  out[i*NOUT + t] = omax;
}

// ---------------- finalize: pos_s, batch, idx (float32 out) -----------------
__global__ void fin_kernel(const float* __restrict__ pos, const int* __restrict__ batch,
                           const int* __restrict__ sel, float* __restrict__ out) {
  int i = blockIdx.x * blockDim.x + threadIdx.x;
  if (i < M_CTR) {
    int s = sel[i];
    int sc = min(max(s, 0), N_PTS - 1);
    out[M_CTR*NOUT + 3*i + 0] = pos[3*sc+0];
    out[M_CTR*NOUT + 3*i + 1] = pos[3*sc+1];
    out[M_CTR*NOUT + 3*i + 2] = pos[3*sc+2];
    out[M_CTR*NOUT + 3*M_CTR + i] = (float)batch[sc];
    out[M_CTR*NOUT + 4*M_CTR + i] = (float)s;
  }
}

extern "C" void kernel_launch(void* const* d_in, const int* in_sizes, int n_in,
                              void* d_out, int out_size, void* d_ws, size_t ws_size,
                              hipStream_t stream) {
  const float* x   = (const float*)d_in[0];
  const float* pos = (const float*)d_in[1];
  const int*  batch= (const int*)d_in[2];
  const float* w1  = (const float*)d_in[3];
  const float* b1  = (const float*)d_in[4];
  const float* g1  = (const float*)d_in[5];
  const float* be1 = (const float*)d_in[6];
  const float* w2  = (const float*)d_in[7];
  const float* b2  = (const float*)d_in[8];
  const float* g2  = (const float*)d_in[9];
  const float* be2 = (const float*)d_in[10];
  float* out = (float*)d_out;

  char*  ws   = (char*)d_ws;
  int*   sel  = (int*)(ws);
  int*   nvld = (int*)(ws + 16384);
  int*   nbr  = (int*)(ws + 32768);
  float* U    = (float*)(ws + 1081344);
  const bool useU = (ws_size >= (size_t)1081344 + (size_t)N_PTS * DIM * 4);

  hipLaunchKernelGGL(fps_kernel,   dim3(1),      dim3(FPS_T), 0, stream, pos, sel);
  hipLaunchKernelGGL(ballq_kernel, dim3(M_CTR),  dim3(64),    0, stream, pos, sel, nbr, nvld);
  if (useU) {
    hipLaunchKernelGGL(xw1_kernel, dim3(N_PTS),  dim3(64),    0, stream, x, w1, U);
    hipLaunchKernelGGL(mlp_u_kernel, dim3(M_CTR), dim3(128),  0, stream,
                       U, pos, w1, b1, g1, be1, w2, b2, g2, be2, sel, nbr, nvld, out);
  } else {
    hipLaunchKernelGGL(mlp_direct_kernel, dim3(M_CTR), dim3(128), 0, stream,
                       x, pos, w1, b1, g1, be1, w2, b2, g2, be2, sel, nbr, nvld, out);
  }
  hipLaunchKernelGGL(fin_kernel,   dim3(16),     dim3(256),   0, stream, pos, batch, sel, out);
}

// Round 12
// 6930.379 us; speedup vs baseline: 1.3165x; 1.1685x over previous
//
#include <hip/hip_runtime.h>
#include <hip/hip_bf16.h>

#define N_PTS 16384
#define M_CTR 4096
#define NIN   64
#define NOUT  128
#define DIM   67
#define KNBR  64
#define R2    0.25f
#define BNI   0.9999950000374997f   // 1/sqrt(1+1e-5)

// ws layout (bytes): sel int[4096] @0 ; nvalid int[4096] @16384 ; nbr int[4096*64] @32768 ;
//                    U float[16384*67] @1081344 (ends 5472256) — used only if ws_size permits

__device__ inline unsigned long long shfl_xor_u64(unsigned long long v, int m){
  int lo = __shfl_xor((int)(unsigned)v, m, 64);
  int hi = __shfl_xor((int)(unsigned)(v >> 32), m, 64);
  return ((unsigned long long)(unsigned)hi << 32) | (unsigned)lo;
}

// DPP-based reduces: VALU-only (no DS pipe), 0-fill identity (valid: operands >= 0)
// ctrl: 0x111=row_shr1 0x112=row_shr2 0x114=row_shr4 0x118=row_shr8
//       0x142=row_bcast15 0x143=row_bcast31
template<int CTRL>
__device__ inline float dpp_fmax(float x){
  int y = __builtin_amdgcn_update_dpp(0, __float_as_int(x), CTRL, 0xF, 0xF, true);
  return fmaxf(x, __int_as_float(y));
}
template<int CTRL>
__device__ inline unsigned dpp_umax(unsigned x){
  unsigned y = (unsigned)__builtin_amdgcn_update_dpp(0, (int)x, CTRL, 0xF, 0xF, true);
  return (x > y) ? x : y;
}

// ---------------- FPS: single block, 1024 thr, DPP reduce tail --------------
#define FPS_T 1024
#define FPS_K (N_PTS / FPS_T)   // 16 points per thread, strided ownership
#define FPS_W (FPS_T / 64)      // 16 waves

__global__ __launch_bounds__(FPS_T, 4) void fps_kernel(const float* __restrict__ pos,
                                                       int* __restrict__ sel) {
  __shared__ unsigned long long wkey[2][FPS_W];   // parity double-buffer
  const int t = threadIdx.x;
  float px[FPS_K], py[FPS_K], pz[FPS_K], dmin[FPS_K];
#pragma unroll
  for (int k = 0; k < FPS_K; k++) {
    int g = t + FPS_T * k;
    px[k] = pos[3*g+0]; py[k] = pos[3*g+1]; pz[k] = pos[3*g+2];
    dmin[k] = 3.4028235e38f;
  }
  if (t == 0) sel[0] = 0;
  float X = pos[0], Y = pos[1], Z = pos[2];
  for (int s = 1; s < M_CTR; s++) {
    // ---- dmin update: exact (p-c)^2, no fma contraction, (xx+yy)+zz order ----
#pragma unroll
    for (int k = 0; k < FPS_K; k++) {
      float dx = __fsub_rn(px[k], X);
      float dy = __fsub_rn(py[k], Y);
      float dz = __fsub_rn(pz[k], Z);
      float q  = __fadd_rn(__fadd_rn(__fmul_rn(dx,dx), __fmul_rn(dy,dy)), __fmul_rn(dz,dz));
      dmin[k]  = fminf(dmin[k], q);
    }
    // ---- deferred argmax: max tree, then earliest-k equality scan ----
    float m0 = fmaxf(fmaxf(dmin[0],  dmin[1]),  fmaxf(dmin[2],  dmin[3]));
    float m1 = fmaxf(fmaxf(dmin[4],  dmin[5]),  fmaxf(dmin[6],  dmin[7]));
    float m2 = fmaxf(fmaxf(dmin[8],  dmin[9]),  fmaxf(dmin[10], dmin[11]));
    float m3 = fmaxf(fmaxf(dmin[12], dmin[13]), fmaxf(dmin[14], dmin[15]));
    float v  = fmaxf(fmaxf(m0, m1), fmaxf(m2, m3));
    int iL = 0;
#pragma unroll
    for (int k = FPS_K - 1; k >= 0; k--) iL = (dmin[k] == v) ? k : iL;  // earliest k wins
    unsigned g = (unsigned)t + ((unsigned)iL << 10);   // my candidate's global index
    // ---- wave reduce via DPP (lane 63 accumulates; readlane broadcasts) ----
    float wv = v;
    wv = dpp_fmax<0x111>(wv);
    wv = dpp_fmax<0x112>(wv);
    wv = dpp_fmax<0x114>(wv);
    wv = dpp_fmax<0x118>(wv);
    wv = dpp_fmax<0x142>(wv);
    wv = dpp_fmax<0x143>(wv);
    const float wv_s = __int_as_float(__builtin_amdgcn_readlane(__float_as_int(wv), 63));
    unsigned cc = (v == wv_s) ? ~g : 0u;     // max(~g) == ~(min g): first-index ties
    cc = dpp_umax<0x111>(cc);
    cc = dpp_umax<0x112>(cc);
    cc = dpp_umax<0x114>(cc);
    cc = dpp_umax<0x118>(cc);
    cc = dpp_umax<0x142>(cc);
    cc = dpp_umax<0x143>(cc);
    const unsigned cw_s = (unsigned)__builtin_amdgcn_readlane((int)cc, 63);
    if ((t & 63) == 0)
      wkey[s & 1][t >> 6] = (((unsigned long long)__float_as_uint(wv_s)) << 32) |
                            (unsigned long long)cw_s;
    __syncthreads();                              // the ONLY barrier this round
    // ---- block reduce: each row of 16 lanes loads all 16 keys, DPP tree ----
    unsigned long long kk = wkey[s & 1][t & 15];
    unsigned khi = (unsigned)(kk >> 32), klo = (unsigned)(kk & 0xFFFFFFFFull);
    unsigned bh = khi;
    bh = dpp_umax<0x111>(bh);
    bh = dpp_umax<0x112>(bh);
    bh = dpp_umax<0x114>(bh);
    bh = dpp_umax<0x118>(bh);                      // lane 63 (row3 lane15) = max hi
    const unsigned bh_s = (unsigned)__builtin_amdgcn_readlane((int)bh, 63);
    unsigned c2 = (khi == bh_s) ? klo : 0u;
    c2 = dpp_umax<0x111>(c2);
    c2 = dpp_umax<0x112>(c2);
    c2 = dpp_umax<0x114>(c2);
    c2 = dpp_umax<0x118>(c2);
    const unsigned bl_s = (unsigned)__builtin_amdgcn_readlane((int)c2, 63);
    const unsigned gw = ~bl_s;
    if (t == 0) sel[s] = (int)gw;
    // same-address global load: one L1-hit fetch, broadcast to all lanes
    X = pos[3*gw+0]; Y = pos[3*gw+1]; Z = pos[3*gw+2];
  }
}

// ---------------- precompute U = x @ w1[:64,:] ------------------------------
__global__ __launch_bounds__(64) void xw1_kernel(const float* __restrict__ x,
                                                 const float* __restrict__ w1,
                                                 float* __restrict__ U) {
  __shared__ float xs[NIN];
  const int n = blockIdx.x, t = threadIdx.x;
  xs[t] = x[n * NIN + t];
  __syncthreads();
  for (int c = t; c < DIM; c += 64) {
    float acc = 0.0f;
#pragma unroll 8
    for (int r = 0; r < NIN; r++) acc = fmaf(xs[r], w1[r * DIM + c], acc);
    U[n * DIM + c] = acc;
  }
}

// ---------------- ball query: one WAVE per centroid -------------------------
#define CAP 2048
__global__ __launch_bounds__(64) void ballq_kernel(const float* __restrict__ pos,
                                                   const int* __restrict__ sel,
                                                   int* __restrict__ nbr,
                                                   int* __restrict__ nvalid) {
  __shared__ unsigned long long keys[CAP];
  __shared__ int cnt;
  const int i = blockIdx.x;
  const int lane = threadIdx.x;
  if (lane == 0) cnt = 0;
  __syncthreads();
  int ci = sel[i]; ci = min(max(ci, 0), N_PTS - 1);
  const float X = pos[3*ci], Y = pos[3*ci+1], Z = pos[3*ci+2];
  for (int k = 0; k < N_PTS / 64; k++) {
    int g = lane + 64 * k;
    float dx = __fsub_rn(pos[3*g+0], X);
    float dy = __fsub_rn(pos[3*g+1], Y);
    float dz = __fsub_rn(pos[3*g+2], Z);
    float q  = __fadd_rn(__fadd_rn(__fmul_rn(dx,dx), __fmul_rn(dy,dy)), __fmul_rn(dz,dz));
    if (q <= R2) {
      int p = atomicAdd(&cnt, 1);
      if (p < CAP)
        keys[p] = (((unsigned long long)__float_as_uint(q)) << 32) | (unsigned)g;
    }
  }
  __syncthreads();
  const int n = min(cnt, CAP);
  for (int r = 0; r < KNBR; r++) {
    unsigned long long mk = ~0ull; int mp = -1;
    for (int p = lane; p < n; p += 64) {
      unsigned long long kk = keys[p];
      if (kk < mk) { mk = kk; mp = p; }
    }
    unsigned long long rk = mk;
#pragma unroll
    for (int m = 32; m >= 1; m >>= 1) {
      unsigned long long o = shfl_xor_u64(rk, m);
      rk = (o < rk) ? o : rk;
    }
    if (rk != ~0ull && rk == mk && mp >= 0) keys[mp] = ~0ull;  // unique winner clears own slot
    if (lane == 0)
      nbr[i * KNBR + r] = (rk != ~0ull) ? (int)(unsigned)(rk & 0xFFFFFFFFull) : 0;
  }
  if (lane == 0) nvalid[i] = min(n, KNBR);
}

// ---------------- MLP (U-precomputed path): w2 column in registers ----------
__global__ __launch_bounds__(128) void mlp_u_kernel(
    const float* __restrict__ U, const float* __restrict__ pos,
    const float* __restrict__ w1, const float* __restrict__ b1,
    const float* __restrict__ g1, const float* __restrict__ be1,
    const float* __restrict__ w2, const float* __restrict__ b2,
    const float* __restrict__ g2, const float* __restrict__ be2,
    const int* __restrict__ sel, const int* __restrict__ nbr,
    const int* __restrict__ nvalid, float* __restrict__ out) {
  __shared__ float Us[KNBR * DIM];
  __shared__ float relx[KNBR], rely[KNBR], relz[KNBR];
  __shared__ float h1[DIM];
  __shared__ float w1r[3][DIM], b1s[DIM], g1s[DIM], be1s[DIM];
  __shared__ int nbrs_s[KNBR];
  const int i = blockIdx.x, t = threadIdx.x;
  int nv = nvalid[i]; nv = min(max(nv, 0), KNBR);
  float w2r[DIM];
#pragma unroll
  for (int c = 0; c < DIM; c++) w2r[c] = w2[c * NOUT + t];
  if (t < KNBR) {
    int nj = (t < nv) ? nbr[i * KNBR + t] : 0;
    nbrs_s[t] = min(max(nj, 0), N_PTS - 1);
  }
  if (t < DIM) {
    w1r[0][t] = w1[64*DIM + t]; w1r[1][t] = w1[65*DIM + t]; w1r[2][t] = w1[66*DIM + t];
    b1s[t] = b1[t]; g1s[t] = g1[t]; be1s[t] = be1[t];
  }
  __syncthreads();
  int ci = sel[i]; ci = min(max(ci, 0), N_PTS - 1);
  const float cx = pos[3*ci], cy = pos[3*ci+1], cz = pos[3*ci+2];
  if (t < KNBR && t < nv) {
    int nj = nbrs_s[t];
    relx[t] = pos[3*nj+0] - cx; rely[t] = pos[3*nj+1] - cy; relz[t] = pos[3*nj+2] - cz;
  }
  for (int e = t; e < nv * DIM; e += 128) {
    int r = e / DIM, c = e - r * DIM;
    Us[e] = U[nbrs_s[r] * DIM + c];
  }
  __syncthreads();
  const float b2d = b2[t], g2d = g2[t], be2d = be2[t];
  float omax = -3.4028235e38f;
  for (int j = 0; j < nv; j++) {
    if (t < DIM) {
      float z = Us[j*DIM + t];
      z = fmaf(relx[j], w1r[0][t], z);
      z = fmaf(rely[j], w1r[1][t], z);
      z = fmaf(relz[j], w1r[2][t], z);
      z += b1s[t];
      z = fmaxf(z, 0.0f);
      h1[t] = g1s[t] * (z * BNI) + be1s[t];
    }
    __syncthreads();
    float a0 = 0.f, a1 = 0.f, a2 = 0.f, a3 = 0.f;
#pragma unroll
    for (int c = 0; c < 64; c += 4) {
      a0 = fmaf(h1[c+0], w2r[c+0], a0);
      a1 = fmaf(h1[c+1], w2r[c+1], a1);
      a2 = fmaf(h1[c+2], w2r[c+2], a2);
      a3 = fmaf(h1[c+3], w2r[c+3], a3);
    }
    a0 = fmaf(h1[64], w2r[64], a0);
    a1 = fmaf(h1[65], w2r[65], a1);
    a2 = fmaf(h1[66], w2r[66], a2);
    float acc = ((a0 + a1) + (a2 + a3)) + b2d;
    float h2v = g2d * (fmaxf(acc, 0.0f) * BNI) + be2d;
    omax = fmaxf(omax, h2v);
    __syncthreads();
  }
  if (nv == 0) omax = 0.0f;
  out[i*NOUT + t] = omax;
}

// ---------------- MLP fallback (reads x directly) ---------------------------
__global__ __launch_bounds__(128) void mlp_direct_kernel(
    const float* __restrict__ x, const float* __restrict__ pos,
    const float* __restrict__ w1, const float* __restrict__ b1,
    const float* __restrict__ g1, const float* __restrict__ be1,
    const float* __restrict__ w2, const float* __restrict__ b2,
    const float* __restrict__ g2, const float* __restrict__ be2,
    const int* __restrict__ sel, const int* __restrict__ nbr,
    const int* __restrict__ nvalid, float* __restrict__ out) {
  __shared__ float xs[NIN];
  __shared__ float h1[DIM];
  __shared__ float rel[3];
  const int i = blockIdx.x, t = threadIdx.x;
  int ci = sel[i]; ci = min(max(ci, 0), N_PTS - 1);
  const float cx = pos[3*ci], cy = pos[3*ci+1], cz = pos[3*ci+2];
  int nv = nvalid[i]; nv = min(max(nv, 0), KNBR);
  float omax = -3.4028235e38f;
  for (int j = 0; j < nv; j++) {
    int nj = nbr[i*KNBR + j]; nj = min(max(nj, 0), N_PTS - 1);
    if (t < NIN) xs[t] = x[nj*NIN + t];
    if (t == 0) { rel[0] = pos[3*nj]-cx; rel[1] = pos[3*nj+1]-cy; rel[2] = pos[3*nj+2]-cz; }
    __syncthreads();
    if (t < DIM) {
      float z = b1[t];
      for (int r = 0; r < NIN; r++) z = fmaf(xs[r], w1[r*DIM + t], z);
      z = fmaf(rel[0], w1[64*DIM + t], z);
      z = fmaf(rel[1], w1[65*DIM + t], z);
      z = fmaf(rel[2], w1[66*DIM + t], z);
      z = fmaxf(z, 0.0f);
      h1[t] = g1[t] * (z * BNI) + be1[t];
    }
    __syncthreads();
    float acc = b2[t];
    for (int c = 0; c < DIM; c++) acc = fmaf(h1[c], w2[c*NOUT + t], acc);
    float h2v = g2[t] * (fmaxf(acc, 0.0f) * BNI) + be2[t];
    omax = fmaxf(omax, h2v);
    __syncthreads();
  }
  if (nv == 0) omax = 0.0f;
  out[i*NOUT + t] = omax;
}

// ---------------- finalize: pos_s, batch, idx (float32 out) -----------------
__global__ void fin_kernel(const float* __restrict__ pos, const int* __restrict__ batch,
                           const int* __restrict__ sel, float* __restrict__ out) {
  int i = blockIdx.x * blockDim.x + threadIdx.x;
  if (i < M_CTR) {
    int s = sel[i];
    int sc = min(max(s, 0), N_PTS - 1);
    out[M_CTR*NOUT + 3*i + 0] = pos[3*sc+0];
    out[M_CTR*NOUT + 3*i + 1] = pos[3*sc+1];
    out[M_CTR*NOUT + 3*i + 2] = pos[3*sc+2];
    out[M_CTR*NOUT + 3*M_CTR + i] = (float)batch[sc];
    out[M_CTR*NOUT + 4*M_CTR + i] = (float)s;
  }
}

extern "C" void kernel_launch(void* const* d_in, const int* in_sizes, int n_in,
                              void* d_out, int out_size, void* d_ws, size_t ws_size,
                              hipStream_t stream) {
  const float* x   = (const float*)d_in[0];
  const float* pos = (const float*)d_in[1];
  const int*  batch= (const int*)d_in[2];
  const float* w1  = (const float*)d_in[3];
  const float* b1  = (const float*)d_in[4];
  const float* g1  = (const float*)d_in[5];
  const float* be1 = (const float*)d_in[6];
  const float* w2  = (const float*)d_in[7];
  const float* b2  = (const float*)d_in[8];
  const float* g2  = (const float*)d_in[9];
  const float* be2 = (const float*)d_in[10];
  float* out = (float*)d_out;

  char*  ws   = (char*)d_ws;
  int*   sel  = (int*)(ws);
  int*   nvld = (int*)(ws + 16384);
  int*   nbr  = (int*)(ws + 32768);
  float* U    = (float*)(ws + 1081344);
  const bool useU = (ws_size >= (size_t)1081344 + (size_t)N_PTS * DIM * 4);

  hipLaunchKernelGGL(fps_kernel,   dim3(1),      dim3(FPS_T), 0, stream, pos, sel);
  hipLaunchKernelGGL(ballq_kernel, dim3(M_CTR),  dim3(64),    0, stream, pos, sel, nbr, nvld);
  if (useU) {
    hipLaunchKernelGGL(xw1_kernel, dim3(N_PTS),  dim3(64),    0, stream, x, w1, U);
    hipLaunchKernelGGL(mlp_u_kernel, dim3(M_CTR), dim3(128),  0, stream,
                       U, pos, w1, b1, g1, be1, w2, b2, g2, be2, sel, nbr, nvld, out);
  } else {
    hipLaunchKernelGGL(mlp_direct_kernel, dim3(M_CTR), dim3(128), 0, stream,
                       x, pos, w1, b1, g1, be1, w2, b2, g2, be2, sel, nbr, nvld, out);
  }
  hipLaunchKernelGGL(fin_kernel,   dim3(16),     dim3(256),   0, stream, pos, batch, sel, out);
}

// Round 13
// 6339.281 us; speedup vs baseline: 1.4392x; 1.0932x over previous
//
#include <hip/hip_runtime.h>
#include <hip/hip_bf16.h>

#define N_PTS 16384
#define M_CTR 4096
#define NIN   64
#define NOUT  128
#define DIM   67
#define KNBR  64
#define R2    0.25f
#define BNI   0.9999950000374997f   // 1/sqrt(1+1e-5)

// ws layout (bytes): sel int[4096] @0 ; nvalid int[4096] @16384 ; nbr int[4096*64] @32768 ;
//                    U float[16384*67] @1081344 (ends 5472256) — used only if ws_size permits

__device__ inline unsigned long long shfl_xor_u64(unsigned long long v, int m){
  int lo = __shfl_xor((int)(unsigned)v, m, 64);
  int hi = __shfl_xor((int)(unsigned)(v >> 32), m, 64);
  return ((unsigned long long)(unsigned)hi << 32) | (unsigned)lo;
}

// DPP-based reduces: VALU-only (no DS pipe), 0-fill identity (valid: operands >= 0)
// ctrl: 0x111=row_shr1 0x112=row_shr2 0x114=row_shr4 0x118=row_shr8
//       0x142=row_bcast15 0x143=row_bcast31
template<int CTRL>
__device__ inline float dpp_fmax(float x){
  int y = __builtin_amdgcn_update_dpp(0, __float_as_int(x), CTRL, 0xF, 0xF, true);
  return fmaxf(x, __int_as_float(y));
}
template<int CTRL>
__device__ inline unsigned dpp_umax(unsigned x){
  unsigned y = (unsigned)__builtin_amdgcn_update_dpp(0, (int)x, CTRL, 0xF, 0xF, true);
  return (x > y) ? x : y;
}

// ---------------- FPS: single block, 1024 thr, DPP reduce tail --------------
#define FPS_T 1024
#define FPS_K (N_PTS / FPS_T)   // 16 points per thread, strided ownership
#define FPS_W (FPS_T / 64)      // 16 waves

// waves_per_eu(4,4): exactly 4 waves/SIMD (grid = 1 block of 1024 = 16 waves/CU).
// Gives the register allocator the full 128-VGPR budget so the 64-float
// per-thread state (px,py,pz,dmin) lives in arch VGPRs — no accvgpr shuffling.
__global__ __launch_bounds__(FPS_T)
__attribute__((amdgpu_waves_per_eu(4, 4)))
void fps_kernel(const float* __restrict__ pos, int* __restrict__ sel) {
  __shared__ unsigned long long wkey[2][FPS_W];   // parity double-buffer
  const int t = threadIdx.x;
  float px[FPS_K], py[FPS_K], pz[FPS_K], dmin[FPS_K];
#pragma unroll
  for (int k = 0; k < FPS_K; k++) {
    int g = t + FPS_T * k;
    px[k] = pos[3*g+0]; py[k] = pos[3*g+1]; pz[k] = pos[3*g+2];
    dmin[k] = 3.4028235e38f;
  }
  if (t == 0) sel[0] = 0;
  float X = pos[0], Y = pos[1], Z = pos[2];
  for (int s = 1; s < M_CTR; s++) {
    // ---- dmin update: exact (p-c)^2, no fma contraction, (xx+yy)+zz order ----
#pragma unroll
    for (int k = 0; k < FPS_K; k++) {
      float dx = __fsub_rn(px[k], X);
      float dy = __fsub_rn(py[k], Y);
      float dz = __fsub_rn(pz[k], Z);
      float q  = __fadd_rn(__fadd_rn(__fmul_rn(dx,dx), __fmul_rn(dy,dy)), __fmul_rn(dz,dz));
      dmin[k]  = fminf(dmin[k], q);
    }
    // ---- deferred argmax: max tree, then earliest-k equality scan ----
    float m0 = fmaxf(fmaxf(dmin[0],  dmin[1]),  fmaxf(dmin[2],  dmin[3]));
    float m1 = fmaxf(fmaxf(dmin[4],  dmin[5]),  fmaxf(dmin[6],  dmin[7]));
    float m2 = fmaxf(fmaxf(dmin[8],  dmin[9]),  fmaxf(dmin[10], dmin[11]));
    float m3 = fmaxf(fmaxf(dmin[12], dmin[13]), fmaxf(dmin[14], dmin[15]));
    float v  = fmaxf(fmaxf(m0, m1), fmaxf(m2, m3));
    int iL = 0;
#pragma unroll
    for (int k = FPS_K - 1; k >= 0; k--) iL = (dmin[k] == v) ? k : iL;  // earliest k wins
    unsigned g = (unsigned)t + ((unsigned)iL << 10);   // my candidate's global index
    // ---- wave reduce via DPP (lane 63 accumulates; readlane broadcasts) ----
    float wv = v;
    wv = dpp_fmax<0x111>(wv);
    wv = dpp_fmax<0x112>(wv);
    wv = dpp_fmax<0x114>(wv);
    wv = dpp_fmax<0x118>(wv);
    wv = dpp_fmax<0x142>(wv);
    wv = dpp_fmax<0x143>(wv);
    const float wv_s = __int_as_float(__builtin_amdgcn_readlane(__float_as_int(wv), 63));
    unsigned cc = (v == wv_s) ? ~g : 0u;     // max(~g) == ~(min g): first-index ties
    cc = dpp_umax<0x111>(cc);
    cc = dpp_umax<0x112>(cc);
    cc = dpp_umax<0x114>(cc);
    cc = dpp_umax<0x118>(cc);
    cc = dpp_umax<0x142>(cc);
    cc = dpp_umax<0x143>(cc);
    const unsigned cw_s = (unsigned)__builtin_amdgcn_readlane((int)cc, 63);
    if ((t & 63) == 0)
      wkey[s & 1][t >> 6] = (((unsigned long long)__float_as_uint(wv_s)) << 32) |
                            (unsigned long long)cw_s;
    __syncthreads();                              // the ONLY barrier this round
    // ---- block reduce: each row of 16 lanes loads all 16 keys, DPP tree ----
    unsigned long long kk = wkey[s & 1][t & 15];
    unsigned khi = (unsigned)(kk >> 32), klo = (unsigned)(kk & 0xFFFFFFFFull);
    unsigned bh = khi;
    bh = dpp_umax<0x111>(bh);
    bh = dpp_umax<0x112>(bh);
    bh = dpp_umax<0x114>(bh);
    bh = dpp_umax<0x118>(bh);                      // lane 63 (row3 lane15) = max hi
    const unsigned bh_s = (unsigned)__builtin_amdgcn_readlane((int)bh, 63);
    unsigned c2 = (khi == bh_s) ? klo : 0u;
    c2 = dpp_umax<0x111>(c2);
    c2 = dpp_umax<0x112>(c2);
    c2 = dpp_umax<0x114>(c2);
    c2 = dpp_umax<0x118>(c2);
    const unsigned bl_s = (unsigned)__builtin_amdgcn_readlane((int)c2, 63);
    const unsigned gw = ~bl_s;
    if (t == 0) sel[s] = (int)gw;
    // same-address global load: one L1-hit fetch, broadcast to all lanes
    X = pos[3*gw+0]; Y = pos[3*gw+1]; Z = pos[3*gw+2];
  }
}

// ---------------- precompute U = x @ w1[:64,:] ------------------------------
__global__ __launch_bounds__(64) void xw1_kernel(const float* __restrict__ x,
                                                 const float* __restrict__ w1,
                                                 float* __restrict__ U) {
  __shared__ float xs[NIN];
  const int n = blockIdx.x, t = threadIdx.x;
  xs[t] = x[n * NIN + t];
  __syncthreads();
  for (int c = t; c < DIM; c += 64) {
    float acc = 0.0f;
#pragma unroll 8
    for (int r = 0; r < NIN; r++) acc = fmaf(xs[r], w1[r * DIM + c], acc);
    U[n * DIM + c] = acc;
  }
}

// ---------------- ball query: one WAVE per centroid -------------------------
#define CAP 2048
__global__ __launch_bounds__(64) void ballq_kernel(const float* __restrict__ pos,
                                                   const int* __restrict__ sel,
                                                   int* __restrict__ nbr,
                                                   int* __restrict__ nvalid) {
  __shared__ unsigned long long keys[CAP];
  __shared__ int cnt;
  const int i = blockIdx.x;
  const int lane = threadIdx.x;
  if (lane == 0) cnt = 0;
  __syncthreads();
  int ci = sel[i]; ci = min(max(ci, 0), N_PTS - 1);
  const float X = pos[3*ci], Y = pos[3*ci+1], Z = pos[3*ci+2];
  for (int k = 0; k < N_PTS / 64; k++) {
    int g = lane + 64 * k;
    float dx = __fsub_rn(pos[3*g+0], X);
    float dy = __fsub_rn(pos[3*g+1], Y);
    float dz = __fsub_rn(pos[3*g+2], Z);
    float q  = __fadd_rn(__fadd_rn(__fmul_rn(dx,dx), __fmul_rn(dy,dy)), __fmul_rn(dz,dz));
    if (q <= R2) {
      int p = atomicAdd(&cnt, 1);
      if (p < CAP)
        keys[p] = (((unsigned long long)__float_as_uint(q)) << 32) | (unsigned)g;
    }
  }
  __syncthreads();
  const int n = min(cnt, CAP);
  for (int r = 0; r < KNBR; r++) {
    unsigned long long mk = ~0ull; int mp = -1;
    for (int p = lane; p < n; p += 64) {
      unsigned long long kk = keys[p];
      if (kk < mk) { mk = kk; mp = p; }
    }
    unsigned long long rk = mk;
#pragma unroll
    for (int m = 32; m >= 1; m >>= 1) {
      unsigned long long o = shfl_xor_u64(rk, m);
      rk = (o < rk) ? o : rk;
    }
    if (rk != ~0ull && rk == mk && mp >= 0) keys[mp] = ~0ull;  // unique winner clears own slot
    if (lane == 0)
      nbr[i * KNBR + r] = (rk != ~0ull) ? (int)(unsigned)(rk & 0xFFFFFFFFull) : 0;
  }
  if (lane == 0) nvalid[i] = min(n, KNBR);
}

// ---------------- MLP (U-precomputed path): w2 column in registers ----------
__global__ __launch_bounds__(128) void mlp_u_kernel(
    const float* __restrict__ U, const float* __restrict__ pos,
    const float* __restrict__ w1, const float* __restrict__ b1,
    const float* __restrict__ g1, const float* __restrict__ be1,
    const float* __restrict__ w2, const float* __restrict__ b2,
    const float* __restrict__ g2, const float* __restrict__ be2,
    const int* __restrict__ sel, const int* __restrict__ nbr,
    const int* __restrict__ nvalid, float* __restrict__ out) {
  __shared__ float Us[KNBR * DIM];
  __shared__ float relx[KNBR], rely[KNBR], relz[KNBR];
  __shared__ float h1[DIM];
  __shared__ float w1r[3][DIM], b1s[DIM], g1s[DIM], be1s[DIM];
  __shared__ int nbrs_s[KNBR];
  const int i = blockIdx.x, t = threadIdx.x;
  int nv = nvalid[i]; nv = min(max(nv, 0), KNBR);
  float w2r[DIM];
#pragma unroll
  for (int c = 0; c < DIM; c++) w2r[c] = w2[c * NOUT + t];
  if (t < KNBR) {
    int nj = (t < nv) ? nbr[i * KNBR + t] : 0;
    nbrs_s[t] = min(max(nj, 0), N_PTS - 1);
  }
  if (t < DIM) {
    w1r[0][t] = w1[64*DIM + t]; w1r[1][t] = w1[65*DIM + t]; w1r[2][t] = w1[66*DIM + t];
    b1s[t] = b1[t]; g1s[t] = g1[t]; be1s[t] = be1[t];
  }
  __syncthreads();
  int ci = sel[i]; ci = min(max(ci, 0), N_PTS - 1);
  const float cx = pos[3*ci], cy = pos[3*ci+1], cz = pos[3*ci+2];
  if (t < KNBR && t < nv) {
    int nj = nbrs_s[t];
    relx[t] = pos[3*nj+0] - cx; rely[t] = pos[3*nj+1] - cy; relz[t] = pos[3*nj+2] - cz;
  }
  for (int e = t; e < nv * DIM; e += 128) {
    int r = e / DIM, c = e - r * DIM;
    Us[e] = U[nbrs_s[r] * DIM + c];
  }
  __syncthreads();
  const float b2d = b2[t], g2d = g2[t], be2d = be2[t];
  float omax = -3.4028235e38f;
  for (int j = 0; j < nv; j++) {
    if (t < DIM) {
      float z = Us[j*DIM + t];
      z = fmaf(relx[j], w1r[0][t], z);
      z = fmaf(rely[j], w1r[1][t], z);
      z = fmaf(relz[j], w1r[2][t], z);
      z += b1s[t];
      z = fmaxf(z, 0.0f);
      h1[t] = g1s[t] * (z * BNI) + be1s[t];
    }
    __syncthreads();
    float a0 = 0.f, a1 = 0.f, a2 = 0.f, a3 = 0.f;
#pragma unroll
    for (int c = 0; c < 64; c += 4) {
      a0 = fmaf(h1[c+0], w2r[c+0], a0);
      a1 = fmaf(h1[c+1], w2r[c+1], a1);
      a2 = fmaf(h1[c+2], w2r[c+2], a2);
      a3 = fmaf(h1[c+3], w2r[c+3], a3);
    }
    a0 = fmaf(h1[64], w2r[64], a0);
    a1 = fmaf(h1[65], w2r[65], a1);
    a2 = fmaf(h1[66], w2r[66], a2);
    float acc = ((a0 + a1) + (a2 + a3)) + b2d;
    float h2v = g2d * (fmaxf(acc, 0.0f) * BNI) + be2d;
    omax = fmaxf(omax, h2v);
    __syncthreads();
  }
  if (nv == 0) omax = 0.0f;
  out[i*NOUT + t] = omax;
}

// ---------------- MLP fallback (reads x directly) ---------------------------
__global__ __launch_bounds__(128) void mlp_direct_kernel(
    const float* __restrict__ x, const float* __restrict__ pos,
    const float* __restrict__ w1, const float* __restrict__ b1,
    const float* __restrict__ g1, const float* __restrict__ be1,
    const float* __restrict__ w2, const float* __restrict__ b2,
    const float* __restrict__ g2, const float* __restrict__ be2,
    const int* __restrict__ sel, const int* __restrict__ nbr,
    const int* __restrict__ nvalid, float* __restrict__ out) {
  __shared__ float xs[NIN];
  __shared__ float h1[DIM];
  __shared__ float rel[3];
  const int i = blockIdx.x, t = threadIdx.x;
  int ci = sel[i]; ci = min(max(ci, 0), N_PTS - 1);
  const float cx = pos[3*ci], cy = pos[3*ci+1], cz = pos[3*ci+2];
  int nv = nvalid[i]; nv = min(max(nv, 0), KNBR);
  float omax = -3.4028235e38f;
  for (int j = 0; j < nv; j++) {
    int nj = nbr[i*KNBR + j]; nj = min(max(nj, 0), N_PTS - 1);
    if (t < NIN) xs[t] = x[nj*NIN + t];
    if (t == 0) { rel[0] = pos[3*nj]-cx; rel[1] = pos[3*nj+1]-cy; rel[2] = pos[3*nj+2]-cz; }
    __syncthreads();
    if (t < DIM) {
      float z = b1[t];
      for (int r = 0; r < NIN; r++) z = fmaf(xs[r], w1[r*DIM + t], z);
      z = fmaf(rel[0], w1[64*DIM + t], z);
      z = fmaf(rel[1], w1[65*DIM + t], z);
      z = fmaf(rel[2], w1[66*DIM + t], z);
      z = fmaxf(z, 0.0f);
      h1[t] = g1[t] * (z * BNI) + be1[t];
    }
    __syncthreads();
    float acc = b2[t];
    for (int c = 0; c < DIM; c++) acc = fmaf(h1[c], w2[c*NOUT + t], acc);
    float h2v = g2[t] * (fmaxf(acc, 0.0f) * BNI) + be2[t];
    omax = fmaxf(omax, h2v);
    __syncthreads();
  }
  if (nv == 0) omax = 0.0f;
  out[i*NOUT + t] = omax;
}

// ---------------- finalize: pos_s, batch, idx (float32 out) -----------------
__global__ void fin_kernel(const float* __restrict__ pos, const int* __restrict__ batch,
                           const int* __restrict__ sel, float* __restrict__ out) {
  int i = blockIdx.x * blockDim.x + threadIdx.x;
  if (i < M_CTR) {
    int s = sel[i];
    int sc = min(max(s, 0), N_PTS - 1);
    out[M_CTR*NOUT + 3*i + 0] = pos[3*sc+0];
    out[M_CTR*NOUT + 3*i + 1] = pos[3*sc+1];
    out[M_CTR*NOUT + 3*i + 2] = pos[3*sc+2];
    out[M_CTR*NOUT + 3*M_CTR + i] = (float)batch[sc];
    out[M_CTR*NOUT + 4*M_CTR + i] = (float)s;
  }
}

extern "C" void kernel_launch(void* const* d_in, const int* in_sizes, int n_in,
                              void* d_out, int out_size, void* d_ws, size_t ws_size,
                              hipStream_t stream) {
  const float* x   = (const float*)d_in[0];
  const float* pos = (const float*)d_in[1];
  const int*  batch= (const int*)d_in[2];
  const float* w1  = (const float*)d_in[3];
  const float* b1  = (const float*)d_in[4];
  const float* g1  = (const float*)d_in[5];
  const float* be1 = (const float*)d_in[6];
  const float* w2  = (const float*)d_in[7];
  const float* b2  = (const float*)d_in[8];
  const float* g2  = (const float*)d_in[9];
  const float* be2 = (const float*)d_in[10];
  float* out = (float*)d_out;

  char*  ws   = (char*)d_ws;
  int*   sel  = (int*)(ws);
  int*   nvld = (int*)(ws + 16384);
  int*   nbr  = (int*)(ws + 32768);
  float* U    = (float*)(ws + 1081344);
  const bool useU = (ws_size >= (size_t)1081344 + (size_t)N_PTS * DIM * 4);

  hipLaunchKernelGGL(fps_kernel,   dim3(1),      dim3(FPS_T), 0, stream, pos, sel);
  hipLaunchKernelGGL(ballq_kernel, dim3(M_CTR),  dim3(64),    0, stream, pos, sel, nbr, nvld);
  if (useU) {
    hipLaunchKernelGGL(xw1_kernel, dim3(N_PTS),  dim3(64),    0, stream, x, w1, U);
    hipLaunchKernelGGL(mlp_u_kernel, dim3(M_CTR), dim3(128),  0, stream,
                       U, pos, w1, b1, g1, be1, w2, b2, g2, be2, sel, nbr, nvld, out);
  } else {
    hipLaunchKernelGGL(mlp_direct_kernel, dim3(M_CTR), dim3(128), 0, stream,
                       x, pos, w1, b1, g1, be1, w2, b2, g2, be2, sel, nbr, nvld, out);
  }
  hipLaunchKernelGGL(fin_kernel,   dim3(16),     dim3(256),   0, stream, pos, batch, sel, out);
}